// Round 3
// baseline (190.767 us; speedup 1.0000x reference)
//
#include <hip/hip_runtime.h>
#include <hip/hip_bf16.h>

// Problem constants
#define Bn 32
#define Cn 32
#define Ln 512
#define INTRA 1024
#define INTER 256
#define DCP 64
#define DDE 512
#define SCALEF 0.05f

typedef __attribute__((ext_vector_type(8))) short short8;
typedef __attribute__((ext_vector_type(4))) float floatx4;

__device__ __forceinline__ short bf16_of(float f) {
    union { float f; unsigned u; } v; v.f = f;
    unsigned r = (v.u + 0x7FFFu + ((v.u >> 16) & 1u)) >> 16;
    return (short)r;
}
__device__ __forceinline__ float f_of_bf16(short h) {
    union { unsigned u; float f; } v;
    v.u = ((unsigned)(unsigned short)h) << 16;
    return v.f;
}

// ---------------------------------------------------------------------------
// Convert weights fp32 -> bf16 (layouts already [n][k] / [m][k] as needed).
// ---------------------------------------------------------------------------
__global__ __launch_bounds__(256) void prep_weights(
    const float* __restrict__ cW1, const float* __restrict__ cW2,
    const float* __restrict__ dW1, const float* __restrict__ dW2,
    short* __restrict__ cW1b, short* __restrict__ cW2b,
    short* __restrict__ dW1b, short* __restrict__ dW2b)
{
    int i = blockIdx.x * 256 + threadIdx.x;
    if (i < 64 * 256) cW1b[i] = bf16_of(cW1[i]);
    if (i < 64 * 64)  cW2b[i] = bf16_of(cW2[i]);
    if (i < DDE * INTRA) { dW1b[i] = bf16_of(dW1[i]); dW2b[i] = bf16_of(dW2[i]); }
}

// ---------------------------------------------------------------------------
// Fused compress (unchanged from round 2): per block, 64 rows of map_raw[c]:
//   T  = relu(tile @ cW1^T + cb1); M1 = T @ cW2^T + cb2
// Store M1 transposed: M1T[c][d][i]  (bf16) — B-operand layout of denoise-1.
// ---------------------------------------------------------------------------
__global__ __launch_bounds__(256) void compress_fused(
    const float* __restrict__ map_raw, const short* __restrict__ cW1b,
    const float* __restrict__ cb1, const short* __restrict__ cW2b,
    const float* __restrict__ cb2, short* __restrict__ M1T)
{
    const int c  = blockIdx.y;
    const int m0 = blockIdx.x * 64;
    const float* A = map_raw + (long)c * INTRA * INTER + (long)m0 * INTER;

    __shared__ short lds[64 * 32 + 64 * 32 + 64 * 64];
    short* Asb = lds;            // [m][k] stride 32
    short* Bsb = lds + 2048;     // [n][k] stride 32
    short* Tsb = lds + 4096;     // [m][k] stride 64

    const int t    = threadIdx.x;
    const int w    = t >> 6;
    const int lane = t & 63;
    const int ln   = lane & 15;
    const int quad = lane >> 4;
    const int sr = t >> 2;
    const int sk = (t & 3) * 8;

    floatx4 acc[4] = {};

    float4 a0 = *(const float4*)(A + sr * INTER + sk);
    float4 a1 = *(const float4*)(A + sr * INTER + sk + 4);
    short8 bpre = *(const short8*)(cW1b + sr * INTER + sk);

    for (int k0 = 0; k0 < INTER; k0 += 32) {
        __syncthreads();
        short8 av;
        av[0] = bf16_of(a0.x); av[1] = bf16_of(a0.y);
        av[2] = bf16_of(a0.z); av[3] = bf16_of(a0.w);
        av[4] = bf16_of(a1.x); av[5] = bf16_of(a1.y);
        av[6] = bf16_of(a1.z); av[7] = bf16_of(a1.w);
        *(short8*)&Asb[sr * 32 + sk] = av;
        *(short8*)&Bsb[sr * 32 + sk] = bpre;
        __syncthreads();

        if (k0 + 32 < INTER) {
            a0 = *(const float4*)(A + sr * INTER + k0 + 32 + sk);
            a1 = *(const float4*)(A + sr * INTER + k0 + 32 + sk + 4);
            bpre = *(const short8*)(cW1b + sr * INTER + k0 + 32 + sk);
        }

        short8 af = *(const short8*)&Asb[(w * 16 + ln) * 32 + quad * 8];
        #pragma unroll
        for (int nt = 0; nt < 4; ++nt) {
            short8 bf = *(const short8*)&Bsb[(nt * 16 + ln) * 32 + quad * 8];
            acc[nt] = __builtin_amdgcn_mfma_f32_16x16x32_bf16(af, bf, acc[nt], 0, 0, 0);
        }
    }

    __syncthreads();

    #pragma unroll
    for (int nt = 0; nt < 4; ++nt) {
        const int n = nt * 16 + ln;
        const float b = cb1[n];
        #pragma unroll
        for (int r = 0; r < 4; ++r) {
            const int m = w * 16 + quad * 4 + r;
            Tsb[m * 64 + n] = bf16_of(fmaxf(acc[nt][r] + b, 0.f));
        }
    }
    {
        const int n = t >> 2, kc = (t & 3) * 16;
        *(short8*)&lds[n * 64 + kc]     = *(const short8*)(cW2b + n * 64 + kc);
        *(short8*)&lds[n * 64 + kc + 8] = *(const short8*)(cW2b + n * 64 + kc + 8);
    }
    __syncthreads();

    floatx4 acc2[4] = {};
    #pragma unroll
    for (int ks = 0; ks < 2; ++ks) {
        short8 af = *(const short8*)&Tsb[(w * 16 + ln) * 64 + ks * 32 + quad * 8];
        #pragma unroll
        for (int nt = 0; nt < 4; ++nt) {
            short8 bf = *(const short8*)&lds[(nt * 16 + ln) * 64 + ks * 32 + quad * 8];
            acc2[nt] = __builtin_amdgcn_mfma_f32_16x16x32_bf16(af, bf, acc2[nt], 0, 0, 0);
        }
    }

    short* outp = M1T + (long)c * 64 * INTRA;
    #pragma unroll
    for (int nt = 0; nt < 4; ++nt) {
        const int n = nt * 16 + ln;
        const float b = cb2[n];
        short t0 = bf16_of(acc2[nt][0] + b);
        short t1 = bf16_of(acc2[nt][1] + b);
        short t2 = bf16_of(acc2[nt][2] + b);
        short t3 = bf16_of(acc2[nt][3] + b);
        const int m = m0 + w * 16 + quad * 4;
        *(short4*)(outp + (long)n * INTRA + m) = make_short4(t0, t1, t2, t3);
    }
}

// ---------------------------------------------------------------------------
// denoise-1: HT[c][d][h] = relu(dW1 @ M1[c] + db1)  (m=h, n=d), BK=64.
// A = dW1b [512][1024] shared; B = M1T[c] [64][1024]; out transposed bf16.
// LDS rows padded to 72 shorts (conflict-floor b128 reads).
// ---------------------------------------------------------------------------
__global__ __launch_bounds__(256) void gemm_dn1(
    const short* __restrict__ A, const short* __restrict__ M1T,
    const float* __restrict__ db1, short* __restrict__ HT)
{
    const int c  = blockIdx.y;
    const int m0 = blockIdx.x * 64;
    const short* Bc = M1T + (long)c * 64 * INTRA;

    __shared__ short Asb[64 * 72];
    __shared__ short Bsb[64 * 72];

    const int t = threadIdx.x, w = t >> 6, lane = t & 63;
    const int ln = lane & 15, quad = lane >> 4;
    const int sr = t >> 2, sk = (t & 3) * 16;

    floatx4 acc[4] = {};
    short8 a0 = *(const short8*)(A + (long)(m0 + sr) * INTRA + sk);
    short8 a1 = *(const short8*)(A + (long)(m0 + sr) * INTRA + sk + 8);
    short8 b0 = *(const short8*)(Bc + (long)sr * INTRA + sk);
    short8 b1 = *(const short8*)(Bc + (long)sr * INTRA + sk + 8);

    for (int k0 = 0; k0 < INTRA; k0 += 64) {
        __syncthreads();
        *(short8*)&Asb[sr * 72 + sk]     = a0;
        *(short8*)&Asb[sr * 72 + sk + 8] = a1;
        *(short8*)&Bsb[sr * 72 + sk]     = b0;
        *(short8*)&Bsb[sr * 72 + sk + 8] = b1;
        __syncthreads();
        const int kn = k0 + 64;
        if (kn < INTRA) {
            a0 = *(const short8*)(A + (long)(m0 + sr) * INTRA + kn + sk);
            a1 = *(const short8*)(A + (long)(m0 + sr) * INTRA + kn + sk + 8);
            b0 = *(const short8*)(Bc + (long)sr * INTRA + kn + sk);
            b1 = *(const short8*)(Bc + (long)sr * INTRA + kn + sk + 8);
        }
        short8 af0 = *(const short8*)&Asb[(w * 16 + ln) * 72 + quad * 8];
        short8 af1 = *(const short8*)&Asb[(w * 16 + ln) * 72 + 32 + quad * 8];
        #pragma unroll
        for (int nt = 0; nt < 4; ++nt) {
            short8 bf0 = *(const short8*)&Bsb[(nt * 16 + ln) * 72 + quad * 8];
            short8 bf1 = *(const short8*)&Bsb[(nt * 16 + ln) * 72 + 32 + quad * 8];
            acc[nt] = __builtin_amdgcn_mfma_f32_16x16x32_bf16(af0, bf0, acc[nt], 0, 0, 0);
            acc[nt] = __builtin_amdgcn_mfma_f32_16x16x32_bf16(af1, bf1, acc[nt], 0, 0, 0);
        }
    }

    float bm[4];
    #pragma unroll
    for (int r = 0; r < 4; ++r) bm[r] = db1[m0 + w * 16 + quad * 4 + r];

    short* outp = HT + (long)c * 64 * DDE;
    #pragma unroll
    for (int nt = 0; nt < 4; ++nt) {
        const int n = nt * 16 + ln;
        float v0 = fmaxf(acc[nt][0] + bm[0], 0.f);
        float v1 = fmaxf(acc[nt][1] + bm[1], 0.f);
        float v2 = fmaxf(acc[nt][2] + bm[2], 0.f);
        float v3 = fmaxf(acc[nt][3] + bm[3], 0.f);
        const int m = m0 + w * 16 + quad * 4;
        *(short4*)(outp + (long)n * DDE + m) =
            make_short4(bf16_of(v0), bf16_of(v1), bf16_of(v2), bf16_of(v3));
    }
}

// ---------------------------------------------------------------------------
// denoise-2 (restructured): m=d (64), n=i (1024 tiles of 64), K=512, BK=64.
// A = HT[c] [64][512] per-c; B = dW2b [1024][512] shared; bias db2[i] on n.
// Output S16[c][i][d] bf16, vectorized short4 stores along d.
// ---------------------------------------------------------------------------
__global__ __launch_bounds__(256) void gemm_dn2(
    const short* __restrict__ HT, const short* __restrict__ dW2b,
    const float* __restrict__ db2, short* __restrict__ S16)
{
    const int c  = blockIdx.y;
    const int n0 = blockIdx.x * 64;
    const short* A = HT + (long)c * 64 * DDE;     // [d][k]
    const short* B = dW2b + (long)n0 * DDE;       // rows i = n0..n0+63

    __shared__ short Asb[64 * 72];
    __shared__ short Bsb[64 * 72];

    const int t = threadIdx.x, w = t >> 6, lane = t & 63;
    const int ln = lane & 15, quad = lane >> 4;
    const int sr = t >> 2, sk = (t & 3) * 16;

    floatx4 acc[4] = {};
    short8 a0 = *(const short8*)(A + (long)sr * DDE + sk);
    short8 a1 = *(const short8*)(A + (long)sr * DDE + sk + 8);
    short8 b0 = *(const short8*)(B + (long)sr * DDE + sk);
    short8 b1 = *(const short8*)(B + (long)sr * DDE + sk + 8);

    for (int k0 = 0; k0 < DDE; k0 += 64) {
        __syncthreads();
        *(short8*)&Asb[sr * 72 + sk]     = a0;
        *(short8*)&Asb[sr * 72 + sk + 8] = a1;
        *(short8*)&Bsb[sr * 72 + sk]     = b0;
        *(short8*)&Bsb[sr * 72 + sk + 8] = b1;
        __syncthreads();
        const int kn = k0 + 64;
        if (kn < DDE) {
            a0 = *(const short8*)(A + (long)sr * DDE + kn + sk);
            a1 = *(const short8*)(A + (long)sr * DDE + kn + sk + 8);
            b0 = *(const short8*)(B + (long)sr * DDE + kn + sk);
            b1 = *(const short8*)(B + (long)sr * DDE + kn + sk + 8);
        }
        short8 af0 = *(const short8*)&Asb[(w * 16 + ln) * 72 + quad * 8];
        short8 af1 = *(const short8*)&Asb[(w * 16 + ln) * 72 + 32 + quad * 8];
        #pragma unroll
        for (int nt = 0; nt < 4; ++nt) {
            short8 bf0 = *(const short8*)&Bsb[(nt * 16 + ln) * 72 + quad * 8];
            short8 bf1 = *(const short8*)&Bsb[(nt * 16 + ln) * 72 + 32 + quad * 8];
            acc[nt] = __builtin_amdgcn_mfma_f32_16x16x32_bf16(af0, bf0, acc[nt], 0, 0, 0);
            acc[nt] = __builtin_amdgcn_mfma_f32_16x16x32_bf16(af1, bf1, acc[nt], 0, 0, 0);
        }
    }

    // C[m=d][n=i] = S[i][d]; bias db2[i]; store bf16 rows [c][i][d]
    #pragma unroll
    for (int nt = 0; nt < 4; ++nt) {
        const int n = n0 + nt * 16 + ln;          // i
        const float bb = db2[n];
        const int m = w * 16 + quad * 4;          // d
        short t0 = bf16_of(acc[nt][0] + bb);
        short t1 = bf16_of(acc[nt][1] + bb);
        short t2 = bf16_of(acc[nt][2] + bb);
        short t3 = bf16_of(acc[nt][3] + bb);
        *(short4*)(S16 + ((long)c * INTRA + n) * DCP + m) = make_short4(t0, t1, t2, t3);
    }
}

// ---------------------------------------------------------------------------
// Fused gather + L1-score + softmax + weighted-sum + blend. S16 bf16 rows.
// Phase 1: wave-per-l-stripe (coalesced 128B row reads).
// Phase 2: wave-cooperative dot + shfl butterfly, lane-latch, coalesced store.
// ---------------------------------------------------------------------------
__global__ __launch_bounds__(256) void fuse_kernel(
    const float* __restrict__ x_loc, const int* __restrict__ indices,
    const short* __restrict__ S16, const float* __restrict__ lamda1,
    const float* __restrict__ lamda2, float* __restrict__ out)
{
    const int c = blockIdx.x;
    const int b = blockIdx.y;

    __shared__ float xs[Ln];
    __shared__ int   idx[Ln];
    __shared__ float red[4][DCP];
    __shared__ float wsm[DCP];

    const int t = threadIdx.x;
    const float* xp = x_loc + ((long)b * Cn + c) * Ln;
    const int*   ip = indices + (long)b * Ln;
    xs[t]        = xp[t];
    xs[t + 256]  = xp[t + 256];
    idx[t]       = ip[t];
    idx[t + 256] = ip[t + 256];
    __syncthreads();

    const short* Sc = S16 + (long)c * INTRA * DCP;

    const int lane = t & 63;
    const int grp  = t >> 6;

    // Phase 1: scores[d] = sum_l |x[l] - S[c][idx[l]][d]|
    float s = 0.f;
    for (int l = grp; l < Ln; l += 4) {
        float g = f_of_bf16(Sc[idx[l] * DCP + lane]);
        s += fabsf(xs[l] - g);
    }
    red[grp][lane] = s;
    __syncthreads();

    if (t < DCP) {
        float sc = red[0][t] + red[1][t] + red[2][t] + red[3][t];
        sc = -sc * (SCALEF * 0.044194173824159216f);  // * 1/sqrt(512)
        float m = sc;
        #pragma unroll
        for (int o = 32; o > 0; o >>= 1) m = fmaxf(m, __shfl_xor(m, o));
        float e = __expf(sc - m);
        float ssum = e;
        #pragma unroll
        for (int o = 32; o > 0; o >>= 1) ssum += __shfl_xor(ssum, o);
        wsm[t] = e / ssum;
    }
    __syncthreads();

    // Phase 2: wave grp owns l in [grp*128, grp*128+128)
    const float wgt  = wsm[lane];
    const float lam1 = 1.f / (1.f + __expf(-lamda1[c]));

    #pragma unroll
    for (int j = 0; j < 2; ++j) {
        const int lbase = grp * 128 + j * 64;
        float res = 0.f;
        #pragma unroll 8
        for (int i = 0; i < 64; ++i) {
            const int l = lbase + i;
            float g = f_of_bf16(Sc[idx[l] * DCP + lane]);
            float v = wgt * g;
            #pragma unroll
            for (int o = 32; o > 0; o >>= 1) v += __shfl_xor(v, o);
            if (lane == i) res = v;
        }
        const int l = lbase + lane;
        const float lam = lam1 * (1.f / (1.f + __expf(-lamda2[l])));
        out[((long)b * Cn + c) * Ln + l] = res * lam + xs[l] * (1.f - lam);
    }
}

// ---------------------------------------------------------------------------
// Launch
// ---------------------------------------------------------------------------
extern "C" void kernel_launch(void* const* d_in, const int* in_sizes, int n_in,
                              void* d_out, int out_size, void* d_ws, size_t ws_size,
                              hipStream_t stream)
{
    const float* x_loc   = (const float*)d_in[0];
    const int*   indices = (const int*)d_in[1];
    const float* map_raw = (const float*)d_in[2];
    const float* cW1     = (const float*)d_in[3];
    const float* cb1     = (const float*)d_in[4];
    const float* cW2     = (const float*)d_in[5];
    const float* cb2     = (const float*)d_in[6];
    const float* dW1     = (const float*)d_in[7];
    const float* db1     = (const float*)d_in[8];
    const float* dW2     = (const float*)d_in[9];
    const float* db2     = (const float*)d_in[10];
    const float* lamda1  = (const float*)d_in[11];
    const float* lamda2  = (const float*)d_in[12];
    float* out = (float*)d_out;

    short* wsS  = (short*)d_ws;
    short* cW1b = wsS;                       // 64*256   = 16384
    short* cW2b = cW1b + 16384;              // 64*64    = 4096
    short* dW1b = cW2b + 4096;               // 512*1024 = 524288
    short* dW2b = dW1b + 524288;             // 1024*512 = 524288
    short* M1T  = dW2b + 524288;             // 32*64*1024 = 2097152
    short* HT   = M1T + 2097152;             // 32*64*512  = 1048576
    short* S16  = HT + 1048576;              // 32*1024*64 = 2097152

    prep_weights<<<2048, 256, 0, stream>>>(cW1, cW2, dW1, dW2,
                                           cW1b, cW2b, dW1b, dW2b);

    compress_fused<<<dim3(INTRA / 64, Cn), 256, 0, stream>>>(
        map_raw, cW1b, cb1, cW2b, cb2, M1T);

    gemm_dn1<<<dim3(DDE / 64, Cn), 256, 0, stream>>>(
        dW1b, M1T, db1, HT);

    gemm_dn2<<<dim3(INTRA / 64, Cn), 256, 0, stream>>>(
        HT, dW2b, db2, S16);

    fuse_kernel<<<dim3(Cn, Bn), 256, 0, stream>>>(
        x_loc, indices, S16, lamda1, lamda2, out);
}

// Round 4
// 141.817 us; speedup vs baseline: 1.3452x; 1.3452x over previous
//
#include <hip/hip_runtime.h>
#include <hip/hip_bf16.h>

// Problem constants
#define Bn 32
#define Cn 32
#define Ln 512
#define INTRA 1024
#define INTER 256
#define DCP 64
#define DDE 512
#define SCALEF 0.05f

typedef __attribute__((ext_vector_type(8))) short short8;
typedef __attribute__((ext_vector_type(4))) float floatx4;

__device__ __forceinline__ short bf16_of(float f) {
    union { float f; unsigned u; } v; v.f = f;
    unsigned r = (v.u + 0x7FFFu + ((v.u >> 16) & 1u)) >> 16;
    return (short)r;
}
__device__ __forceinline__ float f_of_bf16(short h) {
    union { unsigned u; float f; } v;
    v.u = ((unsigned)(unsigned short)h) << 16;
    return v.f;
}

// ---------------------------------------------------------------------------
// Convert weights fp32 -> bf16 (layouts already [n][k] / [m][k] as needed).
// ---------------------------------------------------------------------------
__global__ __launch_bounds__(256) void prep_weights(
    const float* __restrict__ cW1, const float* __restrict__ cW2,
    const float* __restrict__ dW1, const float* __restrict__ dW2,
    short* __restrict__ cW1b, short* __restrict__ cW2b,
    short* __restrict__ dW1b, short* __restrict__ dW2b)
{
    int i = blockIdx.x * 256 + threadIdx.x;
    if (i < 64 * 256) cW1b[i] = bf16_of(cW1[i]);
    if (i < 64 * 64)  cW2b[i] = bf16_of(cW2[i]);
    if (i < DDE * INTRA) { dW1b[i] = bf16_of(dW1[i]); dW2b[i] = bf16_of(dW2[i]); }
}

// ---------------------------------------------------------------------------
// Fused compress: T = relu(tile @ cW1^T + cb1); M1 = T @ cW2^T + cb2.
// Store M1 transposed: M1T[c][d][i] (bf16) — B-operand layout of denoise-1.
// ---------------------------------------------------------------------------
__global__ __launch_bounds__(256) void compress_fused(
    const float* __restrict__ map_raw, const short* __restrict__ cW1b,
    const float* __restrict__ cb1, const short* __restrict__ cW2b,
    const float* __restrict__ cb2, short* __restrict__ M1T)
{
    const int c  = blockIdx.y;
    const int m0 = blockIdx.x * 64;
    const float* A = map_raw + (long)c * INTRA * INTER + (long)m0 * INTER;

    __shared__ short lds[64 * 32 + 64 * 32 + 64 * 64];
    short* Asb = lds;            // [m][k] stride 32
    short* Bsb = lds + 2048;     // [n][k] stride 32
    short* Tsb = lds + 4096;     // [m][k] stride 64

    const int t    = threadIdx.x;
    const int w    = t >> 6;
    const int lane = t & 63;
    const int ln   = lane & 15;
    const int quad = lane >> 4;
    const int sr = t >> 2;
    const int sk = (t & 3) * 8;

    floatx4 acc[4] = {};

    float4 a0 = *(const float4*)(A + sr * INTER + sk);
    float4 a1 = *(const float4*)(A + sr * INTER + sk + 4);
    short8 bpre = *(const short8*)(cW1b + sr * INTER + sk);

    for (int k0 = 0; k0 < INTER; k0 += 32) {
        __syncthreads();
        short8 av;
        av[0] = bf16_of(a0.x); av[1] = bf16_of(a0.y);
        av[2] = bf16_of(a0.z); av[3] = bf16_of(a0.w);
        av[4] = bf16_of(a1.x); av[5] = bf16_of(a1.y);
        av[6] = bf16_of(a1.z); av[7] = bf16_of(a1.w);
        *(short8*)&Asb[sr * 32 + sk] = av;
        *(short8*)&Bsb[sr * 32 + sk] = bpre;
        __syncthreads();

        if (k0 + 32 < INTER) {
            a0 = *(const float4*)(A + sr * INTER + k0 + 32 + sk);
            a1 = *(const float4*)(A + sr * INTER + k0 + 32 + sk + 4);
            bpre = *(const short8*)(cW1b + sr * INTER + k0 + 32 + sk);
        }

        short8 af = *(const short8*)&Asb[(w * 16 + ln) * 32 + quad * 8];
        #pragma unroll
        for (int nt = 0; nt < 4; ++nt) {
            short8 bf = *(const short8*)&Bsb[(nt * 16 + ln) * 32 + quad * 8];
            acc[nt] = __builtin_amdgcn_mfma_f32_16x16x32_bf16(af, bf, acc[nt], 0, 0, 0);
        }
    }

    __syncthreads();

    #pragma unroll
    for (int nt = 0; nt < 4; ++nt) {
        const int n = nt * 16 + ln;
        const float b = cb1[n];
        #pragma unroll
        for (int r = 0; r < 4; ++r) {
            const int m = w * 16 + quad * 4 + r;
            Tsb[m * 64 + n] = bf16_of(fmaxf(acc[nt][r] + b, 0.f));
        }
    }
    {
        const int n = t >> 2, kc = (t & 3) * 16;
        *(short8*)&lds[n * 64 + kc]     = *(const short8*)(cW2b + n * 64 + kc);
        *(short8*)&lds[n * 64 + kc + 8] = *(const short8*)(cW2b + n * 64 + kc + 8);
    }
    __syncthreads();

    floatx4 acc2[4] = {};
    #pragma unroll
    for (int ks = 0; ks < 2; ++ks) {
        short8 af = *(const short8*)&Tsb[(w * 16 + ln) * 64 + ks * 32 + quad * 8];
        #pragma unroll
        for (int nt = 0; nt < 4; ++nt) {
            short8 bf = *(const short8*)&lds[(nt * 16 + ln) * 64 + ks * 32 + quad * 8];
            acc2[nt] = __builtin_amdgcn_mfma_f32_16x16x32_bf16(af, bf, acc2[nt], 0, 0, 0);
        }
    }

    short* outp = M1T + (long)c * 64 * INTRA;
    #pragma unroll
    for (int nt = 0; nt < 4; ++nt) {
        const int n = nt * 16 + ln;
        const float b = cb2[n];
        short t0 = bf16_of(acc2[nt][0] + b);
        short t1 = bf16_of(acc2[nt][1] + b);
        short t2 = bf16_of(acc2[nt][2] + b);
        short t3 = bf16_of(acc2[nt][3] + b);
        const int m = m0 + w * 16 + quad * 4;
        *(short4*)(outp + (long)n * INTRA + m) = make_short4(t0, t1, t2, t3);
    }
}

// ---------------------------------------------------------------------------
// denoise-1: HT[c][d][h] = relu(dW1 @ M1[c] + db1)  (m=h, n=d), BK=64.
// ---------------------------------------------------------------------------
__global__ __launch_bounds__(256) void gemm_dn1(
    const short* __restrict__ A, const short* __restrict__ M1T,
    const float* __restrict__ db1, short* __restrict__ HT)
{
    const int c  = blockIdx.y;
    const int m0 = blockIdx.x * 64;
    const short* Bc = M1T + (long)c * 64 * INTRA;

    __shared__ short Asb[64 * 72];
    __shared__ short Bsb[64 * 72];

    const int t = threadIdx.x, w = t >> 6, lane = t & 63;
    const int ln = lane & 15, quad = lane >> 4;
    const int sr = t >> 2, sk = (t & 3) * 16;

    floatx4 acc[4] = {};
    short8 a0 = *(const short8*)(A + (long)(m0 + sr) * INTRA + sk);
    short8 a1 = *(const short8*)(A + (long)(m0 + sr) * INTRA + sk + 8);
    short8 b0 = *(const short8*)(Bc + (long)sr * INTRA + sk);
    short8 b1 = *(const short8*)(Bc + (long)sr * INTRA + sk + 8);

    for (int k0 = 0; k0 < INTRA; k0 += 64) {
        __syncthreads();
        *(short8*)&Asb[sr * 72 + sk]     = a0;
        *(short8*)&Asb[sr * 72 + sk + 8] = a1;
        *(short8*)&Bsb[sr * 72 + sk]     = b0;
        *(short8*)&Bsb[sr * 72 + sk + 8] = b1;
        __syncthreads();
        const int kn = k0 + 64;
        if (kn < INTRA) {
            a0 = *(const short8*)(A + (long)(m0 + sr) * INTRA + kn + sk);
            a1 = *(const short8*)(A + (long)(m0 + sr) * INTRA + kn + sk + 8);
            b0 = *(const short8*)(Bc + (long)sr * INTRA + kn + sk);
            b1 = *(const short8*)(Bc + (long)sr * INTRA + kn + sk + 8);
        }
        short8 af0 = *(const short8*)&Asb[(w * 16 + ln) * 72 + quad * 8];
        short8 af1 = *(const short8*)&Asb[(w * 16 + ln) * 72 + 32 + quad * 8];
        #pragma unroll
        for (int nt = 0; nt < 4; ++nt) {
            short8 bf0 = *(const short8*)&Bsb[(nt * 16 + ln) * 72 + quad * 8];
            short8 bf1 = *(const short8*)&Bsb[(nt * 16 + ln) * 72 + 32 + quad * 8];
            acc[nt] = __builtin_amdgcn_mfma_f32_16x16x32_bf16(af0, bf0, acc[nt], 0, 0, 0);
            acc[nt] = __builtin_amdgcn_mfma_f32_16x16x32_bf16(af1, bf1, acc[nt], 0, 0, 0);
        }
    }

    float bm[4];
    #pragma unroll
    for (int r = 0; r < 4; ++r) bm[r] = db1[m0 + w * 16 + quad * 4 + r];

    short* outp = HT + (long)c * 64 * DDE;
    #pragma unroll
    for (int nt = 0; nt < 4; ++nt) {
        const int n = nt * 16 + ln;
        float v0 = fmaxf(acc[nt][0] + bm[0], 0.f);
        float v1 = fmaxf(acc[nt][1] + bm[1], 0.f);
        float v2 = fmaxf(acc[nt][2] + bm[2], 0.f);
        float v3 = fmaxf(acc[nt][3] + bm[3], 0.f);
        const int m = m0 + w * 16 + quad * 4;
        *(short4*)(outp + (long)n * DDE + m) =
            make_short4(bf16_of(v0), bf16_of(v1), bf16_of(v2), bf16_of(v3));
    }
}

// ---------------------------------------------------------------------------
// denoise-2: m=d (64), n=i (tiles of 64), K=512. Output S16[c][i][d] bf16.
// ---------------------------------------------------------------------------
__global__ __launch_bounds__(256) void gemm_dn2(
    const short* __restrict__ HT, const short* __restrict__ dW2b,
    const float* __restrict__ db2, short* __restrict__ S16)
{
    const int c  = blockIdx.y;
    const int n0 = blockIdx.x * 64;
    const short* A = HT + (long)c * 64 * DDE;     // [d][k]
    const short* B = dW2b + (long)n0 * DDE;       // rows i = n0..n0+63

    __shared__ short Asb[64 * 72];
    __shared__ short Bsb[64 * 72];

    const int t = threadIdx.x, w = t >> 6, lane = t & 63;
    const int ln = lane & 15, quad = lane >> 4;
    const int sr = t >> 2, sk = (t & 3) * 16;

    floatx4 acc[4] = {};
    short8 a0 = *(const short8*)(A + (long)sr * DDE + sk);
    short8 a1 = *(const short8*)(A + (long)sr * DDE + sk + 8);
    short8 b0 = *(const short8*)(B + (long)sr * DDE + sk);
    short8 b1 = *(const short8*)(B + (long)sr * DDE + sk + 8);

    for (int k0 = 0; k0 < DDE; k0 += 64) {
        __syncthreads();
        *(short8*)&Asb[sr * 72 + sk]     = a0;
        *(short8*)&Asb[sr * 72 + sk + 8] = a1;
        *(short8*)&Bsb[sr * 72 + sk]     = b0;
        *(short8*)&Bsb[sr * 72 + sk + 8] = b1;
        __syncthreads();
        const int kn = k0 + 64;
        if (kn < DDE) {
            a0 = *(const short8*)(A + (long)sr * DDE + kn + sk);
            a1 = *(const short8*)(A + (long)sr * DDE + kn + sk + 8);
            b0 = *(const short8*)(B + (long)sr * DDE + kn + sk);
            b1 = *(const short8*)(B + (long)sr * DDE + kn + sk + 8);
        }
        short8 af0 = *(const short8*)&Asb[(w * 16 + ln) * 72 + quad * 8];
        short8 af1 = *(const short8*)&Asb[(w * 16 + ln) * 72 + 32 + quad * 8];
        #pragma unroll
        for (int nt = 0; nt < 4; ++nt) {
            short8 bf0 = *(const short8*)&Bsb[(nt * 16 + ln) * 72 + quad * 8];
            short8 bf1 = *(const short8*)&Bsb[(nt * 16 + ln) * 72 + 32 + quad * 8];
            acc[nt] = __builtin_amdgcn_mfma_f32_16x16x32_bf16(af0, bf0, acc[nt], 0, 0, 0);
            acc[nt] = __builtin_amdgcn_mfma_f32_16x16x32_bf16(af1, bf1, acc[nt], 0, 0, 0);
        }
    }

    #pragma unroll
    for (int nt = 0; nt < 4; ++nt) {
        const int n = n0 + nt * 16 + ln;          // i
        const float bb = db2[n];
        const int m = w * 16 + quad * 4;          // d
        short t0 = bf16_of(acc[nt][0] + bb);
        short t1 = bf16_of(acc[nt][1] + bb);
        short t2 = bf16_of(acc[nt][2] + bb);
        short t3 = bf16_of(acc[nt][3] + bb);
        *(short4*)(S16 + ((long)c * INTRA + n) * DCP + m) = make_short4(t0, t1, t2, t3);
    }
}

// ---------------------------------------------------------------------------
// Fused gather + L1-score + softmax + weighted-sum + blend.
// Phase 1: short4 gathers (4 rows x 16 d-groups per wave instr), shfl tail.
// Phase 2: MFMA matvec — A = gathered rows (A-frag layout direct from global),
//          B = bf16(w) broadcast over n; n=0 column extracted to LDS.
// ---------------------------------------------------------------------------
__global__ __launch_bounds__(256) void fuse_kernel(
    const float* __restrict__ x_loc, const int* __restrict__ indices,
    const short* __restrict__ S16, const float* __restrict__ lamda1,
    const float* __restrict__ lamda2, float* __restrict__ out)
{
    const int c = blockIdx.x;
    const int b = blockIdx.y;

    __shared__ float xs[Ln];
    __shared__ int   idx[Ln];
    __shared__ float red[4][DCP];
    __shared__ short wbf[DCP];
    __shared__ float ob[Ln];

    const int t = threadIdx.x;
    const float* xp = x_loc + ((long)b * Cn + c) * Ln;
    const int*   ip = indices + (long)b * Ln;
    ((float2*)xs)[t] = ((const float2*)xp)[t];
    ((int2*)idx)[t]  = ((const int2*)ip)[t];
    __syncthreads();

    const short* Sc = S16 + (long)c * INTRA * DCP;
    const int lane = t & 63;
    const int w    = t >> 6;
    const int r    = lane >> 4;    // row-in-group 0..3
    const int dg   = lane & 15;    // d-group: d = dg*4..dg*4+3

    // Phase 1: scores[d] = sum_l |x[l] - S[c][idx[l]][d]|
    float s0 = 0.f, s1 = 0.f, s2 = 0.f, s3 = 0.f;
    #pragma unroll 4
    for (int i = 0; i < 32; ++i) {
        const int lbase = w * 128 + i * 4;
        const int row   = idx[lbase + r];
        short4 g = *(const short4*)(Sc + (long)row * DCP + dg * 4);
        const float x = xs[lbase + r];
        s0 += fabsf(x - f_of_bf16(g.x));
        s1 += fabsf(x - f_of_bf16(g.y));
        s2 += fabsf(x - f_of_bf16(g.z));
        s3 += fabsf(x - f_of_bf16(g.w));
    }
    s0 += __shfl_xor(s0, 16); s0 += __shfl_xor(s0, 32);
    s1 += __shfl_xor(s1, 16); s1 += __shfl_xor(s1, 32);
    s2 += __shfl_xor(s2, 16); s2 += __shfl_xor(s2, 32);
    s3 += __shfl_xor(s3, 16); s3 += __shfl_xor(s3, 32);
    if (lane < 16) {
        red[w][dg * 4 + 0] = s0;
        red[w][dg * 4 + 1] = s1;
        red[w][dg * 4 + 2] = s2;
        red[w][dg * 4 + 3] = s3;
    }
    __syncthreads();

    // Softmax over d (wave 0)
    if (t < DCP) {
        float sc = red[0][t] + red[1][t] + red[2][t] + red[3][t];
        sc = -sc * (SCALEF * 0.044194173824159216f);  // * 1/sqrt(512)
        float m = sc;
        #pragma unroll
        for (int o = 32; o > 0; o >>= 1) m = fmaxf(m, __shfl_xor(m, o));
        float e = __expf(sc - m);
        float ssum = e;
        #pragma unroll
        for (int o = 32; o > 0; o >>= 1) ssum += __shfl_xor(ssum, o);
        wbf[t] = bf16_of(e / ssum);
    }
    __syncthreads();

    // Phase 2: out[l] = sum_d w[d] * G[l][d] via MFMA matvec.
    // B-frag: B[n][k] = w[k] for all n -> same short8 for all ln.
    const int quad = lane >> 4;
    const int ln16 = lane & 15;
    short8 bw0 = *(const short8*)&wbf[quad * 8];
    short8 bw1 = *(const short8*)&wbf[32 + quad * 8];

    #pragma unroll
    for (int mt = 0; mt < 8; ++mt) {
        const int mrow = w * 128 + mt * 16 + ln16;   // l (A-frag m index)
        const short* rp = Sc + (long)idx[mrow] * DCP;
        short8 a0 = *(const short8*)(rp + quad * 8);
        short8 a1 = *(const short8*)(rp + 32 + quad * 8);
        floatx4 acc = {};
        acc = __builtin_amdgcn_mfma_f32_16x16x32_bf16(a0, bw0, acc, 0, 0, 0);
        acc = __builtin_amdgcn_mfma_f32_16x16x32_bf16(a1, bw1, acc, 0, 0, 0);
        if (ln16 == 0) {   // C col n=0 lives in lanes 0,16,32,48; row = quad*4+r'
            const int l0 = w * 128 + mt * 16 + quad * 4;
            ob[l0 + 0] = acc[0];
            ob[l0 + 1] = acc[1];
            ob[l0 + 2] = acc[2];
            ob[l0 + 3] = acc[3];
        }
    }
    __syncthreads();

    // Final blend, coalesced
    const float lam1 = 1.f / (1.f + __expf(-lamda1[c]));
    #pragma unroll
    for (int j = 0; j < 2; ++j) {
        const int l = t + j * 256;
        const float lam = lam1 * (1.f / (1.f + __expf(-lamda2[l])));
        out[((long)b * Cn + c) * Ln + l] = ob[l] * lam + xs[l] * (1.f - lam);
    }
}

// ---------------------------------------------------------------------------
// Launch
// ---------------------------------------------------------------------------
extern "C" void kernel_launch(void* const* d_in, const int* in_sizes, int n_in,
                              void* d_out, int out_size, void* d_ws, size_t ws_size,
                              hipStream_t stream)
{
    const float* x_loc   = (const float*)d_in[0];
    const int*   indices = (const int*)d_in[1];
    const float* map_raw = (const float*)d_in[2];
    const float* cW1     = (const float*)d_in[3];
    const float* cb1     = (const float*)d_in[4];
    const float* cW2     = (const float*)d_in[5];
    const float* cb2     = (const float*)d_in[6];
    const float* dW1     = (const float*)d_in[7];
    const float* db1     = (const float*)d_in[8];
    const float* dW2     = (const float*)d_in[9];
    const float* db2     = (const float*)d_in[10];
    const float* lamda1  = (const float*)d_in[11];
    const float* lamda2  = (const float*)d_in[12];
    float* out = (float*)d_out;

    short* wsS  = (short*)d_ws;
    short* cW1b = wsS;                       // 64*256   = 16384
    short* cW2b = cW1b + 16384;              // 64*64    = 4096
    short* dW1b = cW2b + 4096;               // 512*1024 = 524288
    short* dW2b = dW1b + 524288;             // 1024*512 = 524288
    short* M1T  = dW2b + 524288;             // 32*64*1024 = 2097152
    short* HT   = M1T + 2097152;             // 32*64*512  = 1048576
    short* S16  = HT + 1048576;              // 32*1024*64 = 2097152

    prep_weights<<<2048, 256, 0, stream>>>(cW1, cW2, dW1, dW2,
                                           cW1b, cW2b, dW1b, dW2b);

    compress_fused<<<dim3(INTRA / 64, Cn), 256, 0, stream>>>(
        map_raw, cW1b, cb1, cW2b, cb2, M1T);

    gemm_dn1<<<dim3(DDE / 64, Cn), 256, 0, stream>>>(
        dW1b, M1T, db1, HT);

    gemm_dn2<<<dim3(INTRA / 64, Cn), 256, 0, stream>>>(
        HT, dW2b, db2, S16);

    fuse_kernel<<<dim3(Cn, Bn), 256, 0, stream>>>(
        x_loc, indices, S16, lamda1, lamda2, out);
}